// Round 1
// baseline (744.755 us; speedup 1.0000x reference)
//
#include <hip/hip_runtime.h>
#include <hip/hip_bf16.h>
#include <stdint.h>

#define B_ 256
#define S_ 256
#define D_ 1024
#define P_ 512
#define SH 254            /* S-2 */
#define M_ (B_*SH)        /* 65024 */
#define EPSF 1e-7f

typedef __attribute__((ext_vector_type(8))) short short8v;
typedef __attribute__((ext_vector_type(4))) short short4v;
typedef __attribute__((ext_vector_type(4))) float float4v;

__device__ inline short f2bf(float f) {
  __hip_bfloat16 h = __float2bfloat16(f);
  return *reinterpret_cast<short*>(&h);
}
__device__ inline float bf2f(short u) {
  union { float f; unsigned int i; } c;
  c.i = ((unsigned int)(unsigned short)u) << 16;
  return c.f;
}
__device__ inline float fast_tanh(float x) {
  float e = __expf(2.0f * x);
  return 1.0f - 2.0f * __builtin_amdgcn_rcpf(e + 1.0f);
}

// ---------------- mask dtype detection ----------------
// flag: 0 = int32 mask, 1 = byte (bool) mask, 2 = float32 mask
__global__ void k_detect(const unsigned char* m, int* flag) {
  __shared__ int c0, c3;
  if (threadIdx.x == 0) { c0 = 0; c3 = 0; }
  __syncthreads();
  int f0 = 0, f3 = 0;
  for (int i = threadIdx.x; i < 4096; i += 256) {
    unsigned char v = m[i];
    if (v != 0) {
      if ((i & 3) == 0) f0 = 1;
      if ((i & 3) == 3) f3 = 1;
    }
  }
  if (f0) atomicOr(&c0, 1);
  if (f3) atomicOr(&c3, 1);
  __syncthreads();
  if (threadIdx.x == 0) {
    int f;
    if (c3 == 0) f = 0;        // int32 little-endian 0/1: high bytes all zero
    else if (c0 != 0) f = 1;   // bytes: elements at every offset
    else f = 2;                // float 1.0f: low byte always 0, byte3 = 0x3F
    *flag = f;
  }
}

// ---------------- weight preprocation ----------------
__global__ void k_conv_pcw(const float* wp, const float* wc, short* op, short* oc) {
  int idx = blockIdx.x * 256 + threadIdx.x;   // grid covers 2*D_*P_
  if (idx < D_*P_) op[idx] = f2bf(wp[idx]);
  else { int j = idx - D_*P_; oc[j] = f2bf(wc[j]); }
}

// proj_head (D x P) -> chunked transposed bf16: out[kc*(P*32) + n*32 + kr]
__global__ void k_trans_head(const float* w, short* out) {
  int idx = blockIdx.x * 256 + threadIdx.x;   // D_*P_ threads
  int n = idx & (P_ - 1);
  int k = idx >> 9;
  out[(k >> 5) * (P_*32) + n*32 + (k & 31)] = f2bf(w[k*P_ + n]);
}

// hidden (2 x P x P) -> two chunked transposed bf16 arrays
__global__ void k_trans_hidden(const float* h, short* o0, short* o1) {
  int idx = blockIdx.x * 256 + threadIdx.x;   // 2*P_*P_ threads
  int which = idx >> 18;
  int j = idx & ((P_*P_) - 1);
  int n = j & (P_ - 1);
  int k = j >> 9;
  short v = f2bf(h[which*(P_*P_) + k*P_ + n]);
  short* o = which ? o1 : o0;
  o[(k >> 5) * (P_*32) + n*32 + (k & 31)] = v;
}

// pc[b][p] = x[b,254,:]@proj_prep[:,p] + x[b,255,:]@proj_child[:,p]
__global__ void __launch_bounds__(256) k_pc(const float* __restrict__ x,
                                            const short* __restrict__ wp,
                                            const short* __restrict__ wc,
                                            float* __restrict__ pc) {
  __shared__ float xp[D_], xc[D_];
  int b = blockIdx.x, t = threadIdx.x;
  const float* xb = x + ((size_t)b * S_ + SH) * D_;  // row 254; row 255 follows
  for (int i = t; i < D_; i += 256) { xp[i] = xb[i]; xc[i] = xb[D_ + i]; }
  __syncthreads();
  float a0 = 0.f, a1 = 0.f;
  int p0 = t, p1 = t + 256;
  for (int d = 0; d < D_; d++) {
    float vp = xp[d], vc = xc[d];
    a0 += vp * bf2f(wp[d*P_ + p0]) + vc * bf2f(wc[d*P_ + p0]);
    a1 += vp * bf2f(wp[d*P_ + p1]) + vc * bf2f(wc[d*P_ + p1]);
  }
  pc[b*P_ + p0] = a0;
  pc[b*P_ + p1] = a1;
}

// ---------------- fused 3-GEMM main kernel ----------------
// block: 512 threads (8 waves, 2m x 4n), 64 rows x 512 cols per block
__global__ void __launch_bounds__(512, 2) k_main(
    const float* __restrict__ x, const short* __restrict__ wth,
    const short* __restrict__ h0t, const short* __restrict__ h1t,
    const float* __restrict__ scorer, const float* __restrict__ pc,
    float* __restrict__ scores)
{
  __shared__ __attribute__((aligned(16))) short As[64*40];    // 64 rows x 32k bf16, pitch 40
  __shared__ __attribute__((aligned(16))) short Bs[512*40];   // 512 n x 32k bf16, pitch 40
  __shared__ __attribute__((aligned(16))) short Cs[64*520];   // 64 rows x 512k bf16, pitch 520
  __shared__ float scorer_s[P_];
  __shared__ float score_s[64];

  const int tid  = threadIdx.x;
  const int lane = tid & 63;
  const int w    = tid >> 6;
  const int wm   = w & 1, wn = w >> 1;
  const int l15  = lane & 15, quad = lane >> 4;
  const int rowbase = blockIdx.x * 64;

  if (tid < P_) scorer_s[tid] = scorer[tid];

  // A staging: thread -> (row, 4 floats)
  const int arow = tid >> 3;
  const int acol = (tid & 7) * 4;
  {
  }
  int r0 = rowbase + arow;
  int ab = r0 / SH;
  int as_ = r0 - ab * SH;
  const float* aptr = x + ((size_t)(ab * S_ + as_)) * D_ + acol;

  float4v acc[2][8];
  #pragma unroll
  for (int i = 0; i < 2; i++)
    #pragma unroll
    for (int j = 0; j < 8; j++) acc[i][j] = (float4v){0.f,0.f,0.f,0.f};

  // ---- Stage 1: K = 1024 (32 chunks of 32) ----
  for (int kc = 0; kc < 32; kc++) {
    {
      float4 v = *(const float4*)(aptr + kc*32);
      short4v sv = { f2bf(v.x), f2bf(v.y), f2bf(v.z), f2bf(v.w) };
      *(short4v*)&As[arow*40 + (tid & 7)*4] = sv;
    }
    {
      const uint4* src = (const uint4*)(wth + kc*(P_*32));
      #pragma unroll
      for (int i = 0; i < 4; i++) {
        int c = tid + i*512;
        uint4 v = src[c];
        int n = c >> 2, un = c & 3;
        *(uint4*)&Bs[n*40 + un*8] = v;
      }
    }
    __syncthreads();
    short8v a0 = *(const short8v*)&As[(wm*32 +      l15)*40 + quad*8];
    short8v a1 = *(const short8v*)&As[(wm*32 + 16 + l15)*40 + quad*8];
    #pragma unroll
    for (int nt = 0; nt < 8; nt++) {
      short8v bfr = *(const short8v*)&Bs[(wn*128 + nt*16 + l15)*40 + quad*8];
      acc[0][nt] = __builtin_amdgcn_mfma_f32_16x16x32_bf16(a0, bfr, acc[0][nt], 0, 0, 0);
      acc[1][nt] = __builtin_amdgcn_mfma_f32_16x16x32_bf16(a1, bfr, acc[1][nt], 0, 0, 0);
    }
    __syncthreads();
  }

  // epilogue 1: + pc bias, tanh, -> Cs (bf16)
  #pragma unroll
  for (int mt = 0; mt < 2; mt++) {
    #pragma unroll
    for (int j = 0; j < 4; j++) {
      int rl = wm*32 + mt*16 + quad*4 + j;
      int rg = rowbase + rl;
      int bb = rg / SH;
      const float* pcb = pc + bb*P_;
      #pragma unroll
      for (int nt = 0; nt < 8; nt++) {
        int col = wn*128 + nt*16 + l15;
        float v = fast_tanh(acc[mt][nt][j] + pcb[col]);
        Cs[rl*520 + col] = f2bf(v);
      }
    }
  }
  __syncthreads();

  // ---- Stages 2 & 3: K = 512 (16 chunks), A from Cs ----
  for (int stage = 0; stage < 2; stage++) {
    const short* ht = stage ? h1t : h0t;
    #pragma unroll
    for (int i = 0; i < 2; i++)
      #pragma unroll
      for (int j = 0; j < 8; j++) acc[i][j] = (float4v){0.f,0.f,0.f,0.f};
    for (int kc = 0; kc < 16; kc++) {
      const uint4* src = (const uint4*)(ht + kc*(P_*32));
      #pragma unroll
      for (int i = 0; i < 4; i++) {
        int c = tid + i*512;
        uint4 v = src[c];
        int n = c >> 2, un = c & 3;
        *(uint4*)&Bs[n*40 + un*8] = v;
      }
      __syncthreads();
      short8v a0 = *(const short8v*)&Cs[(wm*32 +      l15)*520 + kc*32 + quad*8];
      short8v a1 = *(const short8v*)&Cs[(wm*32 + 16 + l15)*520 + kc*32 + quad*8];
      #pragma unroll
      for (int nt = 0; nt < 8; nt++) {
        short8v bfr = *(const short8v*)&Bs[(wn*128 + nt*16 + l15)*40 + quad*8];
        acc[0][nt] = __builtin_amdgcn_mfma_f32_16x16x32_bf16(a0, bfr, acc[0][nt], 0, 0, 0);
        acc[1][nt] = __builtin_amdgcn_mfma_f32_16x16x32_bf16(a1, bfr, acc[1][nt], 0, 0, 0);
      }
      __syncthreads();
    }
    if (stage == 0) {
      #pragma unroll
      for (int mt = 0; mt < 2; mt++) {
        #pragma unroll
        for (int j = 0; j < 4; j++) {
          int rl = wm*32 + mt*16 + quad*4 + j;
          #pragma unroll
          for (int nt = 0; nt < 8; nt++) {
            int col = wn*128 + nt*16 + l15;
            Cs[rl*520 + col] = f2bf(fast_tanh(acc[mt][nt][j]));
          }
        }
      }
      __syncthreads();
    }
  }

  // ---- epilogue 3: scorer dot, exp ----
  if (tid < 64) score_s[tid] = 0.f;
  __syncthreads();
  #pragma unroll
  for (int mt = 0; mt < 2; mt++) {
    #pragma unroll
    for (int j = 0; j < 4; j++) {
      float part = 0.f;
      #pragma unroll
      for (int nt = 0; nt < 8; nt++) {
        int col = wn*128 + nt*16 + l15;
        part += fast_tanh(acc[mt][nt][j]) * scorer_s[col];
      }
      #pragma unroll
      for (int o = 1; o < 16; o <<= 1) part += __shfl_xor(part, o, 64);
      if (l15 == 0) atomicAdd(&score_s[wm*32 + mt*16 + quad*4 + j], part);
    }
  }
  __syncthreads();
  if (tid < 64) scores[rowbase + tid] = __expf(score_s[tid]);
}

// ---------------- masked softmax over s ----------------
__global__ void __launch_bounds__(256) k_softmax(const float* __restrict__ scores,
                                                 const void* __restrict__ mask,
                                                 const int* __restrict__ flag,
                                                 float* __restrict__ out) {
  int b = blockIdx.x, t = threadIdx.x;
  int lane = t & 63, w = t >> 6;
  __shared__ float ps[4];
  float me = 0.f;
  bool valid = t < SH;
  if (valid) {
    float e = scores[b*SH + t];
    int f = *flag;
    bool mb;
    if (f == 1)      mb = ((const unsigned char*)mask)[b*S_ + t] != 0;
    else if (f == 2) mb = ((const float*)mask)[b*S_ + t] != 0.0f;
    else             mb = ((const int*)mask)[b*S_ + t] != 0;
    me = mb ? e : 0.f;
  }
  float v = me;
  for (int o = 1; o < 64; o <<= 1) v += __shfl_xor(v, o, 64);
  if (lane == 0) ps[w] = v;
  __syncthreads();
  float tot = ps[0] + ps[1] + ps[2] + ps[3] + EPSF;
  if (valid) out[b*SH + t] = me / tot;
}

extern "C" void kernel_launch(void* const* d_in, const int* in_sizes, int n_in,
                              void* d_out, int out_size, void* d_ws, size_t ws_size,
                              hipStream_t stream) {
  const float* x          = (const float*)d_in[0];
  const float* proj_head  = (const float*)d_in[1];
  const float* proj_prep  = (const float*)d_in[2];
  const float* proj_child = (const float*)d_in[3];
  const float* hidden     = (const float*)d_in[4];
  const float* scorer     = (const float*)d_in[5];
  const void*  mask       = d_in[6];
  float* out = (float*)d_out;
  char* ws = (char*)d_ws;

  // ws layout (all offsets 256B aligned)
  int*   flag   = (int*)  (ws + 0);
  float* pc     = (float*)(ws + 256);        // 256*512*4   = 524288
  short* wth    = (short*)(ws + 524544);     // 512*1024*2  = 1048576
  short* h0t    = (short*)(ws + 1573120);    // 512*512*2   = 524288
  short* h1t    = (short*)(ws + 2097408);    // 512*512*2   = 524288
  short* wpb    = (short*)(ws + 2621696);    // 1024*512*2  = 1048576
  short* wcb    = (short*)(ws + 3670272);    // 1024*512*2  = 1048576
  float* scores = (float*)(ws + 4718848);    // 65024*4     = 260096

  k_detect<<<1, 256, 0, stream>>>((const unsigned char*)mask, flag);
  k_conv_pcw<<<4096, 256, 0, stream>>>(proj_prep, proj_child, wpb, wcb);
  k_trans_head<<<2048, 256, 0, stream>>>(proj_head, wth);
  k_trans_hidden<<<2048, 256, 0, stream>>>(hidden, h0t, h1t);
  k_pc<<<256, 256, 0, stream>>>(x, wpb, wcb, pc);
  k_main<<<1016, 512, 0, stream>>>(x, wth, h0t, h1t, scorer, pc, scores);
  k_softmax<<<256, 256, 0, stream>>>(scores, mask, flag, out);
}